// Round 3
// baseline (2808.820 us; speedup 1.0000x reference)
//
#include <hip/hip_runtime.h>

#define B_ 4
#define C_ 64
#define H_ 192
#define W_ 640
#define C25_ 25
#define HW_ (H_*W_)

// ---------------- weight transposes ----------------
// w[oc][ic][3][3] -> wT[(c*9+k)][oc]
__global__ __launch_bounds__(256) void k_transpose_w3x3(const float* __restrict__ w,
                                                        float* __restrict__ wT, int ic, int total) {
    int idx = blockIdx.x * 256 + threadIdx.x;
    if (idx >= total) return;
    int oc = idx % 25;
    int ck = idx / 25;               // c*9+k
    wT[idx] = w[oc * ic * 9 + ck];
}

// pac_w[o][c][5][5] -> wT[d][c][o]   (d = i*5+j)
__global__ __launch_bounds__(256) void k_transpose_pac(const float* __restrict__ w,
                                                       float* __restrict__ wT) {
    int idx = blockIdx.x * 256 + threadIdx.x;
    if (idx >= 25 * 64 * 64) return;
    int o = idx & 63;
    int c = (idx >> 6) & 63;
    int d = idx >> 12;
    wT[idx] = w[(o * 64 + c) * 25 + d];
}

// ---------------- conv1: x(64ch) -> t1(25ch), relu ----------------
__global__ __launch_bounds__(256) void k_conv1(const float* __restrict__ x,
                                               const float* __restrict__ wT,
                                               float* __restrict__ t1) {
    int b = blockIdx.z, h0 = blockIdx.y * 4, w0 = blockIdx.x * 64;
    int tid = threadIdx.x;
    int ty = tid >> 6, tx = tid & 63;
    __shared__ float xs[8][6][66];
    __shared__ float wl[72][25];
    float acc[25];
#pragma unroll
    for (int i = 0; i < 25; i++) acc[i] = 0.f;

#pragma unroll 1
    for (int cc = 0; cc < 8; cc++) {
        __syncthreads();
        for (int i = tid; i < 8 * 6 * 66; i += 256) {
            int col = i % 66; int r = (i / 66) % 6; int c = i / 396;
            int hh = h0 + r - 1, ww = w0 + col - 1;
            float v = 0.f;
            if (hh >= 0 && hh < H_ && ww >= 0 && ww < W_)
                v = x[((size_t)(b * C_ + cc * 8 + c) * H_ + hh) * W_ + ww];
            xs[c][r][col] = v;
        }
        for (int i = tid; i < 1800; i += 256)
            wl[i / 25][i % 25] = wT[cc * 1800 + i];
        __syncthreads();
#pragma unroll 1
        for (int c = 0; c < 8; c++) {
            float xv[9];
#pragma unroll
            for (int k = 0; k < 9; k++) xv[k] = xs[c][ty + k / 3][tx + k % 3];
#pragma unroll
            for (int oc = 0; oc < 25; oc++) {
#pragma unroll
                for (int k = 0; k < 9; k++) acc[oc] += wl[c * 9 + k][oc] * xv[k];
            }
        }
    }
#pragma unroll
    for (int oc = 0; oc < 25; oc++)
        t1[((size_t)(b * C25_ + oc) * H_ + h0 + ty) * W_ + w0 + tx] = fmaxf(acc[oc], 0.f);
}

// ---------------- per-(b,c) mean / rstd ----------------
__global__ __launch_bounds__(256) void k_stats(const float* __restrict__ t,
                                               float* __restrict__ s) {
    int bc = blockIdx.x;   // 0..99
    const float* p = t + (size_t)bc * HW_;
    float sum = 0.f, sq = 0.f;
    for (int i = threadIdx.x; i < HW_; i += 256) { float v = p[i]; sum += v; sq += v * v; }
    for (int off = 32; off; off >>= 1) {
        sum += __shfl_down(sum, off, 64);
        sq  += __shfl_down(sq,  off, 64);
    }
    __shared__ float r1[4], r2[4];
    int wid = threadIdx.x >> 6, lane = threadIdx.x & 63;
    if (lane == 0) { r1[wid] = sum; r2[wid] = sq; }
    __syncthreads();
    if (threadIdx.x == 0) {
        float S = 0.f, Q = 0.f;
        for (int i = 0; i < 4; i++) { S += r1[i]; Q += r2[i]; }
        float mu = S / (float)HW_;
        float var = Q / (float)HW_ - mu * mu;
        s[bc * 2 + 0] = mu;
        s[bc * 2 + 1] = rsqrtf(fmaxf(var, 0.f) + 1e-5f);
    }
}

// ---------------- conv 25ch -> 25ch with on-load instance norm ----------------
template <int RELU>
__global__ __launch_bounds__(256) void k_conv25(const float* __restrict__ in,
                                                const float* __restrict__ stats,
                                                const float* __restrict__ wT,
                                                const float* __restrict__ bias,
                                                float* __restrict__ out) {
    int b = blockIdx.z, h0 = blockIdx.y * 4, w0 = blockIdx.x * 64;
    int tid = threadIdx.x;
    int ty = tid >> 6, tx = tid & 63;
    __shared__ float xs[5][6][66];
    __shared__ float wl[45][25];
    float acc[25];
#pragma unroll
    for (int i = 0; i < 25; i++) acc[i] = 0.f;

#pragma unroll 1
    for (int cc = 0; cc < 5; cc++) {
        __syncthreads();
        for (int i = tid; i < 5 * 6 * 66; i += 256) {
            int col = i % 66; int r = (i / 66) % 6; int c = i / 396;
            int ch = cc * 5 + c;
            int hh = h0 + r - 1, ww = w0 + col - 1;
            float v = 0.f;
            if (hh >= 0 && hh < H_ && ww >= 0 && ww < W_) {
                float mu = stats[(b * C25_ + ch) * 2 + 0];
                float rs = stats[(b * C25_ + ch) * 2 + 1];
                v = (in[((size_t)(b * C25_ + ch) * H_ + hh) * W_ + ww] - mu) * rs;
            }
            xs[c][r][col] = v;
        }
        for (int i = tid; i < 1125; i += 256)
            wl[i / 25][i % 25] = wT[cc * 1125 + i];
        __syncthreads();
#pragma unroll 1
        for (int c = 0; c < 5; c++) {
            float xv[9];
#pragma unroll
            for (int k = 0; k < 9; k++) xv[k] = xs[c][ty + k / 3][tx + k % 3];
#pragma unroll
            for (int oc = 0; oc < 25; oc++) {
#pragma unroll
                for (int k = 0; k < 9; k++) acc[oc] += wl[c * 9 + k][oc] * xv[k];
            }
        }
    }
#pragma unroll
    for (int oc = 0; oc < 25; oc++) {
        float v = acc[oc] + (bias ? bias[oc] : 0.f);
        if (RELU) v = fmaxf(v, 0.f);
        out[((size_t)(b * C25_ + oc) * H_ + h0 + ty) * W_ + w0 + tx] = v;
    }
}

// ---------------- PAC: out = relu(sum + pac_b) + x ----------------
__global__ __launch_bounds__(256) void k_pac(const float* __restrict__ x,
                                             const float* __restrict__ Kmap,
                                             const float* __restrict__ wT,
                                             const float* __restrict__ pb,
                                             float* __restrict__ out) {
    int b = blockIdx.z, h0 = blockIdx.y * 4, w0 = blockIdx.x * 32;
    int tid = threadIdx.x;
    int og = tid >> 5, pg = tid & 31;   // 8 oc-groups x 32 pixel columns
    __shared__ __align__(16) float Ks[25][32][4];   // [d][col][row]  12.8 KB
    __shared__ __align__(16) float xs[2][8][36];    //                 2.3 KB
    __shared__ __align__(16) float wl[25][2][64];   //                12.8 KB

    for (int i = tid; i < 25 * 32 * 4; i += 256) {
        int r = i & 3, col = (i >> 2) & 31, d = i >> 7;
        Ks[d][col][r] = Kmap[((size_t)(b * C25_ + d) * H_ + h0 + r) * W_ + w0 + col];
    }

    float acc[8][4];
#pragma unroll
    for (int o = 0; o < 8; o++)
#pragma unroll
        for (int k = 0; k < 4; k++) acc[o][k] = 0.f;

#pragma unroll 1
    for (int cc = 0; cc < 32; cc++) {
        __syncthreads();
        for (int i = tid; i < 2 * 8 * 36; i += 256) {
            int col = i % 36; int rc = i / 36;
            int r = rc & 7, c = rc >> 3;
            int hh = h0 + r - 2, ww = w0 + col - 2;
            float v = 0.f;
            if (hh >= 0 && hh < H_ && ww >= 0 && ww < W_)
                v = x[((size_t)(b * C_ + cc * 2 + c) * H_ + hh) * W_ + ww];
            xs[c][r][col] = v;
        }
        for (int i = tid; i < 3200; i += 256) {
            int o = i & 63, c = (i >> 6) & 1, d = i >> 7;
            wl[d][c][o] = wT[((size_t)d * 64 + cc * 2 + c) * 64 + o];
        }
        __syncthreads();
#pragma unroll 1
        for (int dy = 0; dy < 5; dy++) {
#pragma unroll
            for (int dx = 0; dx < 5; dx++) {
                int d = dy * 5 + dx;
                float4 kv4 = *(const float4*)(&Ks[d][pg][0]);
                float kv[4] = {kv4.x, kv4.y, kv4.z, kv4.w};
#pragma unroll
                for (int c = 0; c < 2; c++) {
                    float xk[4];
#pragma unroll
                    for (int k = 0; k < 4; k++) xk[k] = xs[c][k + dy][pg + dx] * kv[k];
                    float4 wa = *(const float4*)(&wl[d][c][og * 8]);
                    float4 wb = *(const float4*)(&wl[d][c][og * 8 + 4]);
                    float wv[8] = {wa.x, wa.y, wa.z, wa.w, wb.x, wb.y, wb.z, wb.w};
#pragma unroll
                    for (int o = 0; o < 8; o++)
#pragma unroll
                        for (int k = 0; k < 4; k++) acc[o][k] += wv[o] * xk[k];
                }
            }
        }
    }

#pragma unroll
    for (int o = 0; o < 8; o++) {
        int oc = og * 8 + o;
        float bias = pb[oc];
#pragma unroll
        for (int k = 0; k < 4; k++) {
            size_t idx = ((size_t)(b * C_ + oc) * H_ + h0 + k) * W_ + w0 + pg;
            out[idx] = fmaxf(acc[o][k] + bias, 0.f) + x[idx];
        }
    }
}

extern "C" void kernel_launch(void* const* d_in, const int* in_sizes, int n_in,
                              void* d_out, int out_size, void* d_ws, size_t ws_size,
                              hipStream_t stream) {
    const float* x   = (const float*)d_in[0];
    const float* w1  = (const float*)d_in[1];
    const float* w2  = (const float*)d_in[2];
    const float* w3  = (const float*)d_in[3];
    const float* b3  = (const float*)d_in[4];
    const float* pw  = (const float*)d_in[5];
    const float* pb  = (const float*)d_in[6];
    float* out = (float*)d_out;
    float* ws  = (float*)d_ws;

    size_t off = 0;
    float* t1  = ws + off; off += (size_t)B_ * C25_ * HW_;   // 12,288,000 fp32 (49.2 MB)
    float* s1  = ws + off; off += 256;
    float* s2  = ws + off; off += 256;
    float* w1T = ws + off; off += 14400;
    float* w2T = ws + off; off += 5632;
    float* w3T = ws + off; off += 5632;
    float* pwT = ws + off; off += 102400;
    // t2 aliases d_out (fp32 out buffer, 125.8 MB; t2 needs 49.2 MB).
    // t2's last read (k_conv25<0>) completes before k_pac rewrites d_out.
    float* t2  = (float*)d_out;
    float* Kmap = t1;   // conv1 output no longer needed when conv3 writes

    k_transpose_w3x3<<<(14400 + 255) / 256, 256, 0, stream>>>(w1, w1T, 64, 14400);
    k_transpose_w3x3<<<(5625 + 255) / 256, 256, 0, stream>>>(w2, w2T, 25, 5625);
    k_transpose_w3x3<<<(5625 + 255) / 256, 256, 0, stream>>>(w3, w3T, 25, 5625);
    k_transpose_pac<<<(102400 + 255) / 256, 256, 0, stream>>>(pw, pwT);

    dim3 gridc(W_ / 64, H_ / 4, B_);
    k_conv1<<<gridc, 256, 0, stream>>>(x, w1T, t1);
    k_stats<<<100, 256, 0, stream>>>(t1, s1);
    k_conv25<1><<<gridc, 256, 0, stream>>>(t1, s1, w2T, nullptr, t2);
    k_stats<<<100, 256, 0, stream>>>(t2, s2);
    k_conv25<0><<<gridc, 256, 0, stream>>>(t2, s2, w3T, b3, Kmap);

    dim3 gridp(W_ / 32, H_ / 4, B_);
    k_pac<<<gridp, 256, 0, stream>>>(x, Kmap, pwT, pb, out);
}

// Round 4
// 1207.737 us; speedup vs baseline: 2.3257x; 2.3257x over previous
//
#include <hip/hip_runtime.h>
#include <hip/hip_bf16.h>

#define B_ 4
#define C_ 64
#define H_ 192
#define W_ 640
#define C25_ 25
#define HW_ (H_*W_)

typedef unsigned short u16;
typedef unsigned int u32;
using short8 = __attribute__((ext_vector_type(8))) short;
using f32x16 = __attribute__((ext_vector_type(16))) float;
using uint4v = __attribute__((ext_vector_type(4))) u32;

__device__ __forceinline__ u16 f2bu(float v) {
    __hip_bfloat16 h = __float2bfloat16(v);
    return *reinterpret_cast<u16*>(&h);
}

// ---------------- weight transposes: w[oc][ic][3][3] -> wT[(c*9+k)][25] ----------------
__global__ __launch_bounds__(256) void k_transpose_w3x3(const float* __restrict__ w,
                                                        float* __restrict__ wT, int ic, int total) {
    int idx = blockIdx.x * 256 + threadIdx.x;
    if (idx >= total) return;
    int oc = idx % 25;
    int ck = idx / 25;
    wT[idx] = w[oc * ic * 9 + ck];
}

// ---------------- pack pac_w into per-lane MFMA A-fragment order (bf16) ----------------
// frag f = (d*4 + ks)*2 + m ; element (lane l, slot j):
//   o = m*32 + (l&31); c = ks*16 + (l>>5)*8 + j;  value = pac_w[o][c][d]
__global__ __launch_bounds__(256) void k_pack_pac(const float* __restrict__ pw,
                                                  u16* __restrict__ pwB) {
    int idx = blockIdx.x * 256 + threadIdx.x;
    if (idx >= 25 * 4 * 2 * 512) return;
    int j = idx & 7, l = (idx >> 3) & 63, f = idx >> 9;
    int m = f & 1, ks = (f >> 1) & 3, d = f >> 3;
    int o = m * 32 + (l & 31);
    int c = ks * 16 + (l >> 5) * 8 + j;
    pwB[idx] = f2bu(pw[(o * 64 + c) * 25 + d]);
}

// ---------------- x NCHW f32 -> xb NHWC bf16 ----------------
__global__ __launch_bounds__(256) void k_x2nhwc(const float* __restrict__ x,
                                                u16* __restrict__ xb) {
    int b = blockIdx.z, h = blockIdx.y, w0 = blockIdx.x * 64;
    __shared__ float t[64][65];
    int tid = threadIdx.x;
    int q = tid >> 6, r = tid & 63;
#pragma unroll 4
    for (int cc = 0; cc < 16; ++cc) {
        int c = cc * 4 + q;                       // read: lanes consecutive w (coalesced)
        t[r][c] = x[(((size_t)b * C_ + c) * H_ + h) * W_ + w0 + r];
    }
    __syncthreads();
#pragma unroll 4
    for (int ww = 0; ww < 16; ++ww) {
        int w = ww * 4 + q;                       // write: lanes consecutive c (coalesced)
        xb[(((size_t)b * H_ + h) * W_ + w0 + w) * 64 + r] = f2bu(t[w][r]);
    }
}

// ---------------- conv1: x(64ch) -> t1(25ch), relu. Scalar-load weights. ----------------
__global__ __launch_bounds__(256) void k_conv1(const float* __restrict__ x,
                                               const float* __restrict__ wT,
                                               float* __restrict__ t1) {
    int b = blockIdx.z, h0 = blockIdx.y * 4, w0 = blockIdx.x * 64;
    int tid = threadIdx.x;
    int ty = tid >> 6, tx = tid & 63;
    __shared__ float xs[8][6][66];
    float acc[25];
#pragma unroll
    for (int i = 0; i < 25; i++) acc[i] = 0.f;

#pragma unroll 1
    for (int cc = 0; cc < 8; cc++) {
        __syncthreads();
        for (int i = tid; i < 8 * 6 * 66; i += 256) {
            int col = i % 66; int r = (i / 66) % 6; int c = i / 396;
            int hh = h0 + r - 1, ww = w0 + col - 1;
            float v = 0.f;
            if (hh >= 0 && hh < H_ && ww >= 0 && ww < W_)
                v = x[((size_t)(b * C_ + cc * 8 + c) * H_ + hh) * W_ + ww];
            xs[c][r][col] = v;
        }
        __syncthreads();
#pragma unroll 1
        for (int c = 0; c < 8; c++) {
            float xv[9];
#pragma unroll
            for (int k = 0; k < 9; k++) xv[k] = xs[c][ty + k / 3][tx + k % 3];
            const float* wp = wT + (size_t)(cc * 8 + c) * 225;   // block-uniform -> s_load
#pragma unroll
            for (int k = 0; k < 9; k++)
#pragma unroll
                for (int oc = 0; oc < 25; oc++) acc[oc] += wp[k * 25 + oc] * xv[k];
        }
    }
#pragma unroll
    for (int oc = 0; oc < 25; oc++)
        t1[((size_t)(b * C25_ + oc) * H_ + h0 + ty) * W_ + w0 + tx] = fmaxf(acc[oc], 0.f);
}

// ---------------- per-(b,c) mean / rstd ----------------
__global__ __launch_bounds__(256) void k_stats(const float* __restrict__ t,
                                               float* __restrict__ s) {
    int bc = blockIdx.x;
    const float* p = t + (size_t)bc * HW_;
    float sum = 0.f, sq = 0.f;
    for (int i = threadIdx.x; i < HW_; i += 256) { float v = p[i]; sum += v; sq += v * v; }
    for (int off = 32; off; off >>= 1) {
        sum += __shfl_down(sum, off, 64);
        sq  += __shfl_down(sq,  off, 64);
    }
    __shared__ float r1[4], r2[4];
    int wid = threadIdx.x >> 6, lane = threadIdx.x & 63;
    if (lane == 0) { r1[wid] = sum; r2[wid] = sq; }
    __syncthreads();
    if (threadIdx.x == 0) {
        float S = 0.f, Q = 0.f;
        for (int i = 0; i < 4; i++) { S += r1[i]; Q += r2[i]; }
        float mu = S / (float)HW_;
        float var = Q / (float)HW_ - mu * mu;
        s[bc * 2 + 0] = mu;
        s[bc * 2 + 1] = rsqrtf(fmaxf(var, 0.f) + 1e-5f);
    }
}

// ---------------- conv 25ch -> 25ch with on-load instance norm ----------------
template <int RELU>
__global__ __launch_bounds__(256) void k_conv25(const float* __restrict__ in,
                                                const float* __restrict__ stats,
                                                const float* __restrict__ wT,
                                                const float* __restrict__ bias,
                                                float* __restrict__ out) {
    int b = blockIdx.z, h0 = blockIdx.y * 4, w0 = blockIdx.x * 64;
    int tid = threadIdx.x;
    int ty = tid >> 6, tx = tid & 63;
    __shared__ float xs[5][6][66];
    float acc[25];
#pragma unroll
    for (int i = 0; i < 25; i++) acc[i] = 0.f;

#pragma unroll 1
    for (int cc = 0; cc < 5; cc++) {
        __syncthreads();
        for (int i = tid; i < 5 * 6 * 66; i += 256) {
            int col = i % 66; int r = (i / 66) % 6; int c = i / 396;
            int ch = cc * 5 + c;
            int hh = h0 + r - 1, ww = w0 + col - 1;
            float v = 0.f;
            if (hh >= 0 && hh < H_ && ww >= 0 && ww < W_) {
                float mu = stats[(b * C25_ + ch) * 2 + 0];
                float rs = stats[(b * C25_ + ch) * 2 + 1];
                v = (in[((size_t)(b * C25_ + ch) * H_ + hh) * W_ + ww] - mu) * rs;
            }
            xs[c][r][col] = v;
        }
        __syncthreads();
#pragma unroll 1
        for (int c = 0; c < 5; c++) {
            float xv[9];
#pragma unroll
            for (int k = 0; k < 9; k++) xv[k] = xs[c][ty + k / 3][tx + k % 3];
            const float* wp = wT + (size_t)(cc * 5 + c) * 225;
#pragma unroll
            for (int k = 0; k < 9; k++)
#pragma unroll
                for (int oc = 0; oc < 25; oc++) acc[oc] += wp[k * 25 + oc] * xv[k];
        }
    }
#pragma unroll
    for (int oc = 0; oc < 25; oc++) {
        float v = acc[oc] + (bias ? bias[oc] : 0.f);
        if (RELU) v = fmaxf(v, 0.f);
        out[((size_t)(b * C25_ + oc) * H_ + h0 + ty) * W_ + w0 + tx] = v;
    }
}

// ---------------- PAC via bf16 MFMA ----------------
// block: 64 oc x (16x32 pixels), 8 waves; wave = 64o x 64p (2x2 32x32 frags)
__device__ __forceinline__ short8 modk(uint4v u, float kv) {
    short8 r;
#pragma unroll
    for (int p = 0; p < 4; ++p) {
        u32 w = u[p];
        float lo = __uint_as_float(w << 16) * kv;
        float hi = __uint_as_float(w & 0xffff0000u) * kv;
        r[2 * p + 0] = (short)f2bu(lo);
        r[2 * p + 1] = (short)f2bu(hi);
    }
    return r;
}

#define XS_U16 (20*36*8*8)   // 46080 u16 = 92160 B (swizzled, [row][col][slot][8])
#define KS_F32 (25*512)      // 51200 B
#define PAC_SMEM (XS_U16*2 + KS_F32*4)   // 143360 B dynamic

__global__ __launch_bounds__(512, 1) void k_pac_mfma(
    const u16* __restrict__ xb, const float* __restrict__ x,
    const float* __restrict__ Kmap, const u16* __restrict__ pwB,
    const float* __restrict__ pb, float* __restrict__ out)
{
    extern __shared__ u16 dsm[];
    u16* xs = dsm;
    float* Ks = (float*)(dsm + XS_U16);
    __shared__ u16 As[2][8 * 512];       // 16 KB static, frag-linear

    const int b = blockIdx.z;
    const int h0 = blockIdx.y * 16, w0 = blockIdx.x * 32;
    const int tid = threadIdx.x, wv = tid >> 6, l = tid & 63;

    // stage xs: bf16, c-contiguous, col-XOR-swizzled 16B slots, zero halo
    for (int i = tid; i < 20 * 36 * 8; i += 512) {
        int s = i & 7, col = (i >> 3) % 36, row = (i >> 3) / 36;
        int h = h0 + row - 2, w = w0 + col - 2;
        int ss = s ^ (col & 7);
        uint4v v = {0, 0, 0, 0};
        if (h >= 0 && h < H_ && w >= 0 && w < W_)
            v = *(const uint4v*)(xb + (((size_t)b * H_ + h) * W_ + w) * 64 + ss * 8);
        *(uint4v*)(xs + i * 8) = v;
    }
    // stage Ks (f32) [25][512]
    for (int i = tid; i < 25 * 512; i += 512) {
        int p = i & 511, d = i >> 9;
        Ks[i] = Kmap[(((size_t)b * C25_ + d) * H_ + h0 + (p >> 5)) * W_ + w0 + (p & 31)];
    }
    // prologue: DMA A-frags for d=0 (wave wv copies frag wv, 16B/lane)
    __builtin_amdgcn_global_load_lds((const u32*)(pwB + (size_t)(0 * 8 + wv) * 512 + l * 8),
                                     (u32*)&As[0][wv * 512], 16, 0, 0);
    __syncthreads();

    f32x16 acc[2][2];
    {
        f32x16 z = {};
        acc[0][0] = z; acc[0][1] = z; acc[1][0] = z; acc[1][1] = z;
    }

    const int col = l & 31;
    int buf = 0;
#pragma unroll 1
    for (int d = 0; d < 25; ++d) {
        if (d + 1 < 25)
            __builtin_amdgcn_global_load_lds(
                (const u32*)(pwB + (size_t)((d + 1) * 8 + wv) * 512 + l * 8),
                (u32*)&As[buf ^ 1][wv * 512], 16, 0, 0);
        int dy = d / 5, dx = d % 5;
        float kv0 = Ks[d * 512 + wv * 64 + col];
        float kv1 = Ks[d * 512 + wv * 64 + 32 + col];
        int xcol = col + dx;
        int sw = xcol & 7;
        int base0 = ((wv * 2 + dy) * 36 + xcol) * 8;
        int base1 = ((wv * 2 + 1 + dy) * 36 + xcol) * 8;
        int cshalf = l >> 5;
#pragma unroll
        for (int ks = 0; ks < 4; ++ks) {
            short8 a0 = *(const short8*)&As[buf][(ks * 2 + 0) * 512 + l * 8];
            short8 a1 = *(const short8*)&As[buf][(ks * 2 + 1) * 512 + l * 8];
            int sl = (ks * 2 + cshalf) ^ sw;
            uint4v u0 = *(const uint4v*)(xs + (base0 + sl) * 8);
            short8 b0 = modk(u0, kv0);
            acc[0][0] = __builtin_amdgcn_mfma_f32_32x32x16_bf16(a0, b0, acc[0][0], 0, 0, 0);
            acc[1][0] = __builtin_amdgcn_mfma_f32_32x32x16_bf16(a1, b0, acc[1][0], 0, 0, 0);
            uint4v u1 = *(const uint4v*)(xs + (base1 + sl) * 8);
            short8 b1 = modk(u1, kv1);
            acc[0][1] = __builtin_amdgcn_mfma_f32_32x32x16_bf16(a0, b1, acc[0][1], 0, 0, 0);
            acc[1][1] = __builtin_amdgcn_mfma_f32_32x32x16_bf16(a1, b1, acc[1][1], 0, 0, 0);
        }
        __syncthreads();   // drains DMA for d+1, protects As[buf] before reuse
        buf ^= 1;
    }

    // epilogue: D layout col=l&31, row=(reg&3)+8*(reg>>2)+4*(l>>5)
#pragma unroll
    for (int m = 0; m < 2; ++m)
#pragma unroll
        for (int n = 0; n < 2; ++n) {
            int h = h0 + wv * 2 + n, w = w0 + col;
#pragma unroll
            for (int r = 0; r < 16; ++r) {
                int o = m * 32 + (r & 3) + 8 * (r >> 2) + 4 * (l >> 5);
                size_t idx = (((size_t)b * C_ + o) * H_ + h) * W_ + w;
                out[idx] = fmaxf(acc[m][n][r] + pb[o], 0.f) + x[idx];
            }
        }
}

extern "C" void kernel_launch(void* const* d_in, const int* in_sizes, int n_in,
                              void* d_out, int out_size, void* d_ws, size_t ws_size,
                              hipStream_t stream) {
    const float* x   = (const float*)d_in[0];
    const float* w1  = (const float*)d_in[1];
    const float* w2  = (const float*)d_in[2];
    const float* w3  = (const float*)d_in[3];
    const float* b3  = (const float*)d_in[4];
    const float* pw  = (const float*)d_in[5];
    const float* pb  = (const float*)d_in[6];
    float* out = (float*)d_out;
    float* ws  = (float*)d_ws;

    size_t off = 0;
    float* t1  = ws + off; off += (size_t)B_ * C25_ * HW_;   // 49.2 MB (also Kmap)
    float* s1  = ws + off; off += 256;
    float* s2  = ws + off; off += 256;
    float* w1T = ws + off; off += 14400;
    float* w2T = ws + off; off += 5632;
    float* w3T = ws + off; off += 5632;
    u16*  pwB  = (u16*)(ws + off); off += 51200;             // 102400 u16
    u16*  xb   = (u16*)(ws + off); off += (size_t)B_ * HW_ * C_ / 2;  // 62.9 MB
    // t2 aliases d_out (out f32 = 125.8 MB >> 49.2 MB needed); fully rewritten by k_pac_mfma
    float* t2  = (float*)d_out;
    float* Kmap = t1;

    k_transpose_w3x3<<<(14400 + 255) / 256, 256, 0, stream>>>(w1, w1T, 64, 14400);
    k_transpose_w3x3<<<(5625 + 255) / 256, 256, 0, stream>>>(w2, w2T, 25, 5625);
    k_transpose_w3x3<<<(5625 + 255) / 256, 256, 0, stream>>>(w3, w3T, 25, 5625);
    k_pack_pac<<<(102400 + 255) / 256, 256, 0, stream>>>(pw, pwB);
    k_x2nhwc<<<dim3(W_ / 64, H_, B_), 256, 0, stream>>>(x, xb);

    dim3 gridc(W_ / 64, H_ / 4, B_);
    k_conv1<<<gridc, 256, 0, stream>>>(x, w1T, t1);
    k_stats<<<100, 256, 0, stream>>>(t1, s1);
    k_conv25<1><<<gridc, 256, 0, stream>>>(t1, s1, w2T, nullptr, t2);
    k_stats<<<100, 256, 0, stream>>>(t2, s2);
    k_conv25<0><<<gridc, 256, 0, stream>>>(t2, s2, w3T, b3, Kmap);

    k_pac_mfma<<<dim3(W_ / 32, H_ / 16, B_), 512, PAC_SMEM, stream>>>(
        xb, x, Kmap, pwB, pb, out);
}

// Round 7
// 682.924 us; speedup vs baseline: 4.1129x; 1.7685x over previous
//
#include <hip/hip_runtime.h>
#include <hip/hip_bf16.h>

#define B_ 4
#define C_ 64
#define H_ 192
#define W_ 640
#define C25_ 25
#define HW_ (H_*W_)

typedef unsigned short u16;
typedef unsigned int u32;
using short8 = __attribute__((ext_vector_type(8))) short;
using f32x16 = __attribute__((ext_vector_type(16))) float;
using uint4v = __attribute__((ext_vector_type(4))) u32;

__device__ __forceinline__ u16 f2bu(float v) {
    __hip_bfloat16 h = __float2bfloat16(v);
    return *reinterpret_cast<u16*>(&h);
}
__device__ __forceinline__ float bf16lo(u32 w) { return __uint_as_float(w << 16); }
__device__ __forceinline__ float bf16hi(u32 w) { return __uint_as_float(w & 0xffff0000u); }

// ================= small prep kernels =================
__global__ __launch_bounds__(512) void k_zero(float* __restrict__ p, int n) {
    int i = blockIdx.x * 512 + threadIdx.x;
    if (i < n) p[i] = 0.f;
}

// w1[25][64][3][3] -> A-frags [36][512]: f=tap*4+kc; o=l&31, c=kc*16+(l>>5)*8+j
__global__ __launch_bounds__(256) void k_pack_w1(const float* __restrict__ w,
                                                 u16* __restrict__ wB) {
    int idx = blockIdx.x * 256 + threadIdx.x;
    if (idx >= 36 * 512) return;
    int j = idx & 7, l = (idx >> 3) & 63, f = idx >> 9;
    int tap = f >> 2, kc = f & 3;
    int o = l & 31, c = kc * 16 + (l >> 5) * 8 + j;
    float val = (o < 25) ? w[(o * 64 + c) * 9 + tap] : 0.f;
    wB[idx] = f2bu(val);
}

// w[25][25][3][3] * rs_{b,c} -> A-frags [4b][18][512]: f=tap*2+kc
__global__ __launch_bounds__(256) void k_pack_w25(const float* __restrict__ w,
                                                  const float* __restrict__ partial,
                                                  u16* __restrict__ wB) {
    int idx = blockIdx.x * 256 + threadIdx.x;
    if (idx >= 4 * 18 * 512) return;
    int j = idx & 7, l = (idx >> 3) & 63, f2 = idx >> 9;
    int f = f2 % 18, b = f2 / 18;
    int tap = f >> 1, kc = f & 1;
    int o = l & 31, c = kc * 16 + (l >> 5) * 8 + j;
    float val = 0.f;
    if (o < 25 && c < 25) {
        float S = partial[(b * 32 + c) * 2], Q = partial[(b * 32 + c) * 2 + 1];
        float mu = S / (float)HW_;
        float var = Q / (float)HW_ - mu * mu;
        float rs = rsqrtf(fmaxf(var, 0.f) + 1e-5f);
        val = w[(o * 25 + c) * 9 + tap] * rs;
    }
    wB[idx] = f2bu(val);
}

// per-(b,o) epilogue constant: -sum_{c,k} w*rs*mu (+ bias)
__global__ void k_cst(const float* __restrict__ w, const float* __restrict__ partial,
                      const float* __restrict__ bias, float* __restrict__ cst) {
    int t = threadIdx.x;  // 128
    if (t >= 128) return;
    int b = t >> 5, o = t & 31;
    float acc = 0.f;
    if (o < 25) {
        for (int c = 0; c < 25; ++c) {
            float S = partial[(b * 32 + c) * 2], Q = partial[(b * 32 + c) * 2 + 1];
            float mu = S / (float)HW_;
            float var = Q / (float)HW_ - mu * mu;
            float rs = rsqrtf(fmaxf(var, 0.f) + 1e-5f);
            float wsum = 0.f;
            for (int k = 0; k < 9; ++k) wsum += w[(o * 25 + c) * 9 + k];
            acc += wsum * rs * mu;
        }
    }
    cst[b * 32 + o] = -acc + ((bias && o < 25) ? bias[o] : 0.f);
}

// mu (bf16) per (b,c) for halo padding
__global__ void k_mus(const float* __restrict__ partial, u16* __restrict__ muB) {
    int t = threadIdx.x;  // 128
    if (t >= 128) return;
    muB[t] = f2bu(partial[t * 2] * (1.f / (float)HW_));
}

// pac_w packing (unchanged, proven)
__global__ __launch_bounds__(256) void k_pack_pac(const float* __restrict__ pw,
                                                  u16* __restrict__ pwB) {
    int idx = blockIdx.x * 256 + threadIdx.x;
    if (idx >= 25 * 4 * 2 * 512) return;
    int j = idx & 7, l = (idx >> 3) & 63, f = idx >> 9;
    int m = f & 1, ks = (f >> 1) & 3, d = f >> 3;
    int o = m * 32 + (l & 31);
    int c = ks * 16 + (l >> 5) * 8 + j;
    pwB[idx] = f2bu(pw[(o * 64 + c) * 25 + d]);
}

// x NCHW f32 -> xb NHWC bf16 (unchanged, proven)
__global__ __launch_bounds__(256) void k_x2nhwc(const float* __restrict__ x,
                                                u16* __restrict__ xb) {
    int b = blockIdx.z, h = blockIdx.y, w0 = blockIdx.x * 64;
    __shared__ float t[64][65];
    int tid = threadIdx.x;
    int q = tid >> 6, r = tid & 63;
#pragma unroll 4
    for (int cc = 0; cc < 16; ++cc) {
        int c = cc * 4 + q;
        t[r][c] = x[(((size_t)b * C_ + c) * H_ + h) * W_ + w0 + r];
    }
    __syncthreads();
#pragma unroll 4
    for (int ww = 0; ww < 16; ++ww) {
        int w = ww * 4 + q;
        xb[(((size_t)b * H_ + h) * W_ + w0 + w) * 64 + r] = f2bu(t[w][r]);
    }
}

// ================= conv via MFMA =================
// block 512 thr (8 waves), tile 16 rows x 32 cols, M=32 oc, per-wave rows {2wv,2wv+1}
template <int KC, int RELU, int OUT_NHWC, int MUPAD, int PERB>
__global__ __launch_bounds__(512, 2) void k_conv_mfma(
    const u16* __restrict__ in, const u16* __restrict__ Afrag,
    const float* __restrict__ cst, const u16* __restrict__ muB,
    u16* __restrict__ outb, float* __restrict__ outf)
{
    constexpr int SLOTS = KC * 2;       // 16B chunks per pixel
    constexpr int CS = SLOTS * 8;       // channel stride
    constexpr int NF = 9 * KC;
    extern __shared__ u16 dsm[];
    u16* xs = dsm;                      // [18][36][SLOTS][8]
    u16* As = dsm + 18 * 36 * SLOTS * 8;  // [NF][512]

    const int b = blockIdx.z;
    const int h0 = blockIdx.y * 16, w0 = blockIdx.x * 32;
    const int tid = threadIdx.x, wv = tid >> 6, l = tid & 63;

    // stage A-frags (plain vector copy; tiny vs pixel staging)
    const u16* Ab = Afrag + (PERB ? (size_t)b * NF * 512 : 0);
    for (int i = tid; i < NF * 128; i += 512)
        ((uint4v*)As)[i] = ((const uint4v*)Ab)[i];

    for (int i = tid; i < 18 * 36 * SLOTS; i += 512) {
        int s = i % SLOTS; int col = (i / SLOTS) % 36; int row = (i / SLOTS) / 36;
        int h = h0 + row - 1, w = w0 + col - 1;
        int ss = s ^ (col & (SLOTS - 1));
        uint4v v;
        if (h >= 0 && h < H_ && w >= 0 && w < W_) {
            v = *(const uint4v*)(in + (((size_t)b * H_ + h) * W_ + w) * CS + ss * 8);
        } else if (MUPAD) {
            v = *(const uint4v*)(muB + b * 32 + ss * 8);
        } else {
            v = uint4v{0, 0, 0, 0};
        }
        *(uint4v*)(xs + i * 8) = v;
    }
    __syncthreads();

    f32x16 acc0 = {}, acc1 = {};
    const int colp = l & 31, half = l >> 5;
#pragma unroll 1
    for (int tap = 0; tap < 9; ++tap) {
        int dy = tap / 3, dx = tap % 3;
        int xcol = colp + dx;
        int sw = xcol & (SLOTS - 1);
        int rbase = (wv * 2 + dy) * 36 + xcol;
#pragma unroll
        for (int kc = 0; kc < KC; ++kc) {
            short8 a = *(const short8*)(As + (tap * KC + kc) * 512 + l * 8);
            int sl = (kc * 2 + half) ^ sw;
            short8 b0 = *(const short8*)(xs + (rbase * SLOTS + sl) * 8);
            short8 b1 = *(const short8*)(xs + ((rbase + 36) * SLOTS + sl) * 8);
            acc0 = __builtin_amdgcn_mfma_f32_32x32x16_bf16(a, b0, acc0, 0, 0, 0);
            acc1 = __builtin_amdgcn_mfma_f32_32x32x16_bf16(a, b1, acc1, 0, 0, 0);
        }
    }

    const float* cb = cst ? cst + b * 32 : nullptr;
#pragma unroll
    for (int n = 0; n < 2; ++n) {
        int h = h0 + wv * 2 + n, w = w0 + colp;
        const f32x16& ac = n ? acc1 : acc0;
        if (OUT_NHWC) {
            size_t base = (((size_t)b * H_ + h) * W_ + w) * 32;
#pragma unroll
            for (int rp = 0; rp < 8; ++rp) {
                int r = rp * 2;
                int o0 = (r & 3) + 8 * (r >> 2) + 4 * half;
                float v0 = ac[r] + (cb ? cb[o0] : 0.f);
                float v1 = ac[r + 1] + (cb ? cb[o0 + 1] : 0.f);
                if (RELU) { v0 = fmaxf(v0, 0.f); v1 = fmaxf(v1, 0.f); }
                if (o0 >= 25) v0 = 0.f;
                if (o0 + 1 >= 25) v1 = 0.f;
                u32 pk = (u32)f2bu(v0) | ((u32)f2bu(v1) << 16);
                *(u32*)(outb + base + o0) = pk;
            }
        } else {
#pragma unroll
            for (int r = 0; r < 16; ++r) {
                int o = (r & 3) + 8 * (r >> 2) + 4 * half;
                if (o < 25)
                    outf[(((size_t)b * C25_ + o) * H_ + h) * W_ + w] =
                        ac[r] + (cb ? cb[o] : 0.f);
            }
        }
    }
}

// ================= stats over NHWC bf16 (atomic partials) =================
__global__ __launch_bounds__(256) void k_stats_nhwc(const u16* __restrict__ t,
                                                    float* __restrict__ partial) {
    int b = blockIdx.x / 48, slab = blockIdx.x % 48;   // 4 rows per slab
    int cq = threadIdx.x & 7, g = threadIdx.x >> 3;    // cq: 4-channel quad, g 0..31
    size_t pix0 = ((size_t)b * H_ + slab * 4) * W_;
    float s0 = 0, s1 = 0, s2 = 0, s3 = 0, q0 = 0, q1 = 0, q2 = 0, q3 = 0;
    for (int p = g; p < 4 * W_; p += 32) {
        const u16* ptr = t + (pix0 + p) * 32 + cq * 4;
        u32 wa = *(const u32*)ptr, wb = *(const u32*)(ptr + 2);
        float v0 = bf16lo(wa), v1 = bf16hi(wa), v2 = bf16lo(wb), v3 = bf16hi(wb);
        s0 += v0; q0 += v0 * v0;
        s1 += v1; q1 += v1 * v1;
        s2 += v2; q2 += v2 * v2;
        s3 += v3; q3 += v3 * v3;
    }
#pragma unroll
    for (int m = 8; m <= 32; m <<= 1) {
        s0 += __shfl_xor(s0, m); q0 += __shfl_xor(q0, m);
        s1 += __shfl_xor(s1, m); q1 += __shfl_xor(q1, m);
        s2 += __shfl_xor(s2, m); q2 += __shfl_xor(q2, m);
        s3 += __shfl_xor(s3, m); q3 += __shfl_xor(q3, m);
    }
    if ((threadIdx.x & 63) < 8) {
        float sv[4] = {s0, s1, s2, s3}, qv[4] = {q0, q1, q2, q3};
#pragma unroll
        for (int i = 0; i < 4; ++i) {
            int c = cq * 4 + i;
            if (c < 25) {
                atomicAdd(&partial[(b * 32 + c) * 2 + 0], sv[i]);
                atomicAdd(&partial[(b * 32 + c) * 2 + 1], qv[i]);
            }
        }
    }
}

// ================= PAC via bf16 MFMA (unchanged, proven) =================
__device__ __forceinline__ short8 modk(uint4v u, float kv) {
    short8 r;
#pragma unroll
    for (int p = 0; p < 4; ++p) {
        u32 w = u[p];
        float lo = __uint_as_float(w << 16) * kv;
        float hi = __uint_as_float(w & 0xffff0000u) * kv;
        r[2 * p + 0] = (short)f2bu(lo);
        r[2 * p + 1] = (short)f2bu(hi);
    }
    return r;
}

#define XS_U16 (20*36*8*8)
#define KS_F32 (25*512)
#define PAC_SMEM (XS_U16*2 + KS_F32*4)

__global__ __launch_bounds__(512, 1) void k_pac_mfma(
    const u16* __restrict__ xb, const float* __restrict__ x,
    const float* __restrict__ Kmap, const u16* __restrict__ pwB,
    const float* __restrict__ pb, float* __restrict__ out)
{
    extern __shared__ u16 dsm[];
    u16* xs = dsm;
    float* Ks = (float*)(dsm + XS_U16);
    __shared__ u16 As[2][8 * 512];

    const int b = blockIdx.z;
    const int h0 = blockIdx.y * 16, w0 = blockIdx.x * 32;
    const int tid = threadIdx.x, wv = tid >> 6, l = tid & 63;

    for (int i = tid; i < 20 * 36 * 8; i += 512) {
        int s = i & 7, col = (i >> 3) % 36, row = (i >> 3) / 36;
        int h = h0 + row - 2, w = w0 + col - 2;
        int ss = s ^ (col & 7);
        uint4v v = {0, 0, 0, 0};
        if (h >= 0 && h < H_ && w >= 0 && w < W_)
            v = *(const uint4v*)(xb + (((size_t)b * H_ + h) * W_ + w) * 64 + ss * 8);
        *(uint4v*)(xs + i * 8) = v;
    }
    for (int i = tid; i < 25 * 512; i += 512) {
        int p = i & 511, d = i >> 9;
        Ks[i] = Kmap[(((size_t)b * C25_ + d) * H_ + h0 + (p >> 5)) * W_ + w0 + (p & 31)];
    }
    __builtin_amdgcn_global_load_lds((const u32*)(pwB + (size_t)(0 * 8 + wv) * 512 + l * 8),
                                     (u32*)&As[0][wv * 512], 16, 0, 0);
    __syncthreads();

    f32x16 acc[2][2];
    {
        f32x16 z = {};
        acc[0][0] = z; acc[0][1] = z; acc[1][0] = z; acc[1][1] = z;
    }

    const int col = l & 31;
    int buf = 0;
#pragma unroll 1
    for (int d = 0; d < 25; ++d) {
        if (d + 1 < 25)
            __builtin_amdgcn_global_load_lds(
                (const u32*)(pwB + (size_t)((d + 1) * 8 + wv) * 512 + l * 8),
                (u32*)&As[buf ^ 1][wv * 512], 16, 0, 0);
        int dy = d / 5, dx = d % 5;
        float kv0 = Ks[d * 512 + wv * 64 + col];
        float kv1 = Ks[d * 512 + wv * 64 + 32 + col];
        int xcol = col + dx;
        int sw = xcol & 7;
        int base0 = ((wv * 2 + dy) * 36 + xcol) * 8;
        int base1 = ((wv * 2 + 1 + dy) * 36 + xcol) * 8;
        int cshalf = l >> 5;
#pragma unroll
        for (int ks = 0; ks < 4; ++ks) {
            short8 a0 = *(const short8*)&As[buf][(ks * 2 + 0) * 512 + l * 8];
            short8 a1 = *(const short8*)&As[buf][(ks * 2 + 1) * 512 + l * 8];
            int sl = (ks * 2 + cshalf) ^ sw;
            uint4v u0 = *(const uint4v*)(xs + (base0 + sl) * 8);
            short8 b0 = modk(u0, kv0);
            acc[0][0] = __builtin_amdgcn_mfma_f32_32x32x16_bf16(a0, b0, acc[0][0], 0, 0, 0);
            acc[1][0] = __builtin_amdgcn_mfma_f32_32x32x16_bf16(a1, b0, acc[1][0], 0, 0, 0);
            uint4v u1 = *(const uint4v*)(xs + (base1 + sl) * 8);
            short8 b1 = modk(u1, kv1);
            acc[0][1] = __builtin_amdgcn_mfma_f32_32x32x16_bf16(a0, b1, acc[0][1], 0, 0, 0);
            acc[1][1] = __builtin_amdgcn_mfma_f32_32x32x16_bf16(a1, b1, acc[1][1], 0, 0, 0);
        }
        __syncthreads();
        buf ^= 1;
    }

#pragma unroll
    for (int m = 0; m < 2; ++m)
#pragma unroll
        for (int n = 0; n < 2; ++n) {
            int h = h0 + wv * 2 + n, w = w0 + col;
#pragma unroll
            for (int r = 0; r < 16; ++r) {
                int o = m * 32 + (r & 3) + 8 * (r >> 2) + 4 * (l >> 5);
                size_t idx = (((size_t)b * C_ + o) * H_ + h) * W_ + w;
                out[idx] = fmaxf(acc[m][n][r] + pb[o], 0.f) + x[idx];
            }
        }
}

// ================= launch =================
extern "C" void kernel_launch(void* const* d_in, const int* in_sizes, int n_in,
                              void* d_out, int out_size, void* d_ws, size_t ws_size,
                              hipStream_t stream) {
    const float* x   = (const float*)d_in[0];
    const float* w1  = (const float*)d_in[1];
    const float* w2  = (const float*)d_in[2];
    const float* w3  = (const float*)d_in[3];
    const float* b3  = (const float*)d_in[4];
    const float* pw  = (const float*)d_in[5];
    const float* pb  = (const float*)d_in[6];
    float* out = (float*)d_out;
    float* ws  = (float*)d_ws;

    size_t off = 0;
    float* Kmap = ws + off; off += (size_t)B_ * C25_ * HW_;          // 49.2 MB
    u16*  xb   = (u16*)(ws + off); off += (size_t)B_ * HW_ * C_ / 2; // 62.9 MB
    u16*  pwB  = (u16*)(ws + off); off += 51200;
    u16*  w1B  = (u16*)(ws + off); off += 9216;
    u16*  w2B  = (u16*)(ws + off); off += 18432;
    u16*  w3B  = (u16*)(ws + off); off += 18432;
    float* part1 = ws + off; off += 256;
    float* part2 = ws + off; off += 256;
    float* cst2  = ws + off; off += 128;
    float* cst3  = ws + off; off += 128;
    u16*  mu1B = (u16*)(ws + off); off += 64;
    u16*  mu2B = (u16*)(ws + off); off += 64;

    // conv intermediates (NHWC bf16, c padded to 32) live in d_out:
    // both dead before k_pac_mfma overwrites d_out.
    u16* t1b = (u16*)d_out;                       // 31.5 MB
    u16* t2b = (u16*)d_out + (size_t)B_ * HW_ * 32;

    k_zero<<<1, 512, 0, stream>>>(part1, 512);    // zeros part1+part2 (contiguous)
    k_pack_w1<<<72, 256, 0, stream>>>(w1, w1B);
    k_pack_pac<<<400, 256, 0, stream>>>(pw, pwB);
    k_x2nhwc<<<dim3(W_ / 64, H_, B_), 256, 0, stream>>>(x, xb);

    dim3 gridc(W_ / 32, H_ / 16, B_);
    const int smem1  = (18 * 36 * 8 * 8 + 36 * 512) * 2;   // 119808 B
    const int smem25 = (18 * 36 * 4 * 8 + 18 * 512) * 2;   // 59904 B

    k_conv_mfma<4, 1, 1, 0, 0><<<gridc, 512, smem1, stream>>>(
        xb, w1B, nullptr, nullptr, t1b, nullptr);

    k_stats_nhwc<<<B_ * 48, 256, 0, stream>>>(t1b, part1);
    k_mus<<<1, 128, 0, stream>>>(part1, mu1B);
    k_pack_w25<<<144, 256, 0, stream>>>(w2, part1, w2B);
    k_cst<<<1, 128, 0, stream>>>(w2, part1, nullptr, cst2);

    k_conv_mfma<2, 1, 1, 1, 1><<<gridc, 512, smem25, stream>>>(
        t1b, w2B, cst2, mu1B, t2b, nullptr);

    k_stats_nhwc<<<B_ * 48, 256, 0, stream>>>(t2b, part2);
    k_mus<<<1, 128, 0, stream>>>(part2, mu2B);
    k_pack_w25<<<144, 256, 0, stream>>>(w3, part2, w3B);
    k_cst<<<1, 128, 0, stream>>>(w3, part2, b3, cst3);

    k_conv_mfma<2, 0, 0, 1, 1><<<gridc, 512, smem25, stream>>>(
        t2b, w3B, cst3, mu2B, nullptr, Kmap);

    k_pac_mfma<<<gridc, 512, PAC_SMEM, stream>>>(xb, x, Kmap, pwB, pb, out);
}